// Round 13
// baseline (85.373 us; speedup 1.0000x reference)
//
#include <hip/hip_runtime.h>
#include <hip/hip_bf16.h>
#include <stdint.h>

#define M_DIM 8192
#define N_DIM 2048
#define K_DIM 2048
#define NT    (K_DIM / 64)   // 32 K-tiles of BK=64

typedef float f32x4 __attribute__((ext_vector_type(4)));
typedef short bf16x8 __attribute__((ext_vector_type(8)));

typedef const __attribute__((address_space(1))) char* gp_t;
typedef __attribute__((address_space(3))) char* lp_t;

static __device__ __forceinline__ void gload_lds16(const void* g, void* l) {
  __builtin_amdgcn_global_load_lds((gp_t)(uintptr_t)g, (lp_t)(uint32_t)(uintptr_t)l, 16, 0, 0);
}

// round-to-nearest-even f32 -> bf16 bits (exact for -1, 0, +1)
static __device__ __forceinline__ unsigned short f2bf(float f) {
  unsigned int u = __float_as_uint(f);
  unsigned int r = (u + 0x7FFFu + ((u >> 16) & 1u)) >> 16;
  return (unsigned short)r;
}

// ---------------- fused: x -> bf16 (blocks 0..16383) + |W| partials (blocks 16384..17407) ----
__global__ void cvt_x_absum(const float* __restrict__ x, unsigned short* __restrict__ xb,
                            const float* __restrict__ w, float* __restrict__ partials) {
  const int b = blockIdx.x;
  if (b < 16384) {
    int tid = b * 256 + threadIdx.x;
    float4 v = ((const float4*)x)[tid];
    ushort4 o;
    o.x = f2bf(v.x); o.y = f2bf(v.y); o.z = f2bf(v.z); o.w = f2bf(v.w);
    ((ushort4*)xb)[tid] = o;
  } else {
    int tid = (b - 16384) * 256 + threadIdx.x;
    const float4* w4 = (const float4*)w;
    float s = 0.f;
#pragma unroll
    for (int i = 0; i < 4; ++i) {
      float4 v = w4[tid + i * 262144];
      s += fabsf(v.x) + fabsf(v.y) + fabsf(v.z) + fabsf(v.w);
    }
#pragma unroll
    for (int off = 32; off > 0; off >>= 1) s += __shfl_down(s, off, 64);
    __shared__ float ls[4];
    if ((threadIdx.x & 63) == 0) ls[threadIdx.x >> 6] = s;
    __syncthreads();
    if (threadIdx.x == 0) partials[b - 16384] = (ls[0] + ls[1]) + (ls[2] + ls[3]);
  }
}

// ---------------- W -> ternary bf16 {-1,0,1}; each block self-reduces scale ----------------
__global__ void quant_w(const float* __restrict__ w, const float* __restrict__ partials,
                        unsigned short* __restrict__ wt, float* __restrict__ scale_out) {
  __shared__ float ls[4];
  float s = 0.f;
#pragma unroll
  for (int i = 0; i < 4; ++i) s += partials[threadIdx.x + i * 256];
#pragma unroll
  for (int off = 32; off > 0; off >>= 1) s += __shfl_down(s, off, 64);
  if ((threadIdx.x & 63) == 0) ls[threadIdx.x >> 6] = s;
  __syncthreads();
  const float scale = ((ls[0] + ls[1]) + (ls[2] + ls[3])) * (1.0f / 4194304.0f);
  if (blockIdx.x == 0 && threadIdx.x == 0) scale_out[0] = scale;

  const float inv = 1.0f / (scale + 1e-10f);
  int tid = blockIdx.x * 256 + threadIdx.x;
  float4 v = ((const float4*)w)[tid];
  ushort4 o;
  float t;
  t = fminf(1.f, fmaxf(-1.f, rintf(v.x * inv))); o.x = f2bf(t);
  t = fminf(1.f, fmaxf(-1.f, rintf(v.y * inv))); o.y = f2bf(t);
  t = fminf(1.f, fmaxf(-1.f, rintf(v.z * inv))); o.z = f2bf(t);
  t = fminf(1.f, fmaxf(-1.f, rintf(v.w * inv))); o.w = f2bf(t);
  ((ushort4*)wt)[tid] = o;
}

// ---------------- 256x256 GEMM: 1 barrier/tile, both operands staged 1-tile-ahead ----------
// BM=BN=256, BK=64, 8 waves (2Mx4N), 512 thr, LDS 128KB dbuf, XOR swizzle (0 conflicts),
// K-loop x2 unrolled. SA and SB both target buf[cb^1] (tile t-1's data, consumed at the
// t-1 end barrier) -> no mid-tile WAR hazard -> single tile-end VMCNT(0)+barrier. Without
// the mid-tile lockstep, waves slide phases so ds_reads overlap other waves' MFMA.

#define VMCNT(n) asm volatile("s_waitcnt vmcnt(" #n ")" ::: "memory")
#define FENCE    asm volatile("" ::: "memory")
#define BARRIER  do { FENCE; __builtin_amdgcn_s_barrier(); FENCE; } while (0)

#define READ_A(base, mh, dst)                                                                   \
  do {                                                                                          \
    _Pragma("unroll") for (int i = 0; i < 4; ++i) {                                             \
      dst[i][0] = *(const bf16x8*)((base) + (wr * 128 + (mh) * 64 + i * 16) * 128 + rd0);       \
      dst[i][1] = *(const bf16x8*)((base) + (wr * 128 + (mh) * 64 + i * 16) * 128 + rd1);       \
    }                                                                                           \
  } while (0)

#define READ_B(base, nh, dst)                                                                   \
  do {                                                                                          \
    _Pragma("unroll") for (int j = 0; j < 2; ++j) {                                             \
      dst[j][0] = *(const bf16x8*)((base) + (wc * 64 + (nh) * 32 + j * 16) * 128 + rd0);        \
      dst[j][1] = *(const bf16x8*)((base) + (wc * 64 + (nh) * 32 + j * 16) * 128 + rd1);        \
    }                                                                                           \
  } while (0)

#define MFMA_Q(mh, nh, ar, br)                                                                  \
  do {                                                                                          \
    __builtin_amdgcn_s_setprio(1);                                                              \
    _Pragma("unroll") for (int i = 0; i < 4; ++i)                                               \
      _Pragma("unroll") for (int j = 0; j < 2; ++j)                                             \
        acc[(mh) * 4 + i][(nh) * 2 + j] = __builtin_amdgcn_mfma_f32_16x16x32_bf16(              \
            ar[i][0], br[j][0], acc[(mh) * 4 + i][(nh) * 2 + j], 0, 0, 0);                      \
    _Pragma("unroll") for (int i = 0; i < 4; ++i)                                               \
      _Pragma("unroll") for (int j = 0; j < 2; ++j)                                             \
        acc[(mh) * 4 + i][(nh) * 2 + j] = __builtin_amdgcn_mfma_f32_16x16x32_bf16(              \
            ar[i][1], br[j][1], acc[(mh) * 4 + i][(nh) * 2 + j], 0, 0, 0);                      \
    __builtin_amdgcn_s_setprio(0);                                                              \
  } while (0)

// stage half-tiles: linear LDS dest (gload_lds requirement), inverse-swizzled global source
#define SA(bufsel, r) gload_lds16(Ag + offA[r] + ktA, ldsb + (bufsel) * 65536 + tid * 16 + (r) * 8192)
#define SB(bufsel, r) gload_lds16(Bg + offB[r] + ktB, ldsb + (bufsel) * 65536 + 32768 + tid * 16 + (r) * 8192)

// one K-tile body: compute buf[CURSEL]; stage tile t+1 (A and B) into buf[NXTSEL].
#define TILE_BODY(CURSEL, NXTSEL, t)                                                            \
  do {                                                                                          \
    const char* curA = ldsb + (CURSEL) * 65536;                                                 \
    const char* curB = curA + 32768;                                                            \
    READ_A(curA, 0, a0);                                                                        \
    READ_B(curB, 0, b0);                                                                        \
    if ((t) < NT - 1) { SA(NXTSEL, 0); SA(NXTSEL, 1); }                                         \
    MFMA_Q(0, 0, a0, b0);                                                                       \
    READ_B(curB, 1, b1);                                                                        \
    if ((t) < NT - 1) { SA(NXTSEL, 2); SA(NXTSEL, 3); ktA += 128; }                             \
    MFMA_Q(0, 1, a0, b1);                                                                       \
    READ_A(curA, 1, a1);                                                                        \
    if ((t) < NT - 1) { SB(NXTSEL, 0); SB(NXTSEL, 1); }                                         \
    MFMA_Q(1, 0, a1, b0);                                                                       \
    if ((t) < NT - 1) { SB(NXTSEL, 2); SB(NXTSEL, 3); ktB += 128; }                             \
    MFMA_Q(1, 1, a1, b1);                                                                       \
    VMCNT(0); /* drain tile t+1's 8 loads (issued 500-2500 cyc ago, L2/LLC-resident) */         \
    BARRIER;  /* single tile-boundary barrier: buf[NXTSEL] valid, tile-t regs consumed */       \
  } while (0)

__global__ void __launch_bounds__(512, 2)
gemm_bt(const unsigned short* __restrict__ A, const unsigned short* __restrict__ Bt,
        const float* __restrict__ bias, const float* __restrict__ scale_p,
        float* __restrict__ out) {
  __shared__ __align__(16) char lds_raw[131072];
  char* ldsb = (char*)lds_raw;

  const int tid = threadIdx.x;                 // 0..511
  const int lane = tid & 63;
  const int wid = tid >> 6;                    // 0..7
  const int wr = wid >> 2;                     // 0..1
  const int wc = wid & 3;                      // 0..3
  const int l15 = lane & 15, lhi = lane >> 4;

  // 3-bit read swizzle: byte ^= (row&7)<<4 ; row&7 == l15&7 (row offsets are x16)
  const int swzl = (l15 & 7) << 4;
  const int rd0 = l15 * 128 + ((lhi * 16) ^ swzl);          // k-half 0
  const int rd1 = l15 * 128 + (((lhi * 16) ^ 64) ^ swzl);   // k-half 1 (XOR, not +64!)

  // XCD-aware swizzle: 256 blocks, 8 XCDs x 32-chunk; bm-major inside chunk
  const int bid = blockIdx.x;
  const int swz = (bid & 7) * 32 + (bid >> 3);
  const int bm = swz >> 3;                     // 0..31
  const int bn = swz & 7;                      // 0..7
  const int m0 = bm << 8, n0 = bn << 8;

  // staging: thread stages LDS row srow+r*64, colbyte (tid&7)*16 (linear dest);
  // global source column inverse-swizzled so swizzled ds_reads see linear data.
  const int srow = tid >> 3;                                          // 0..63
  const int scol = (((tid & 7) ^ ((tid >> 3) & 7)) << 4);             // cb ^ (row&7)<<4
  const char* Ag = (const char*)A;
  const char* Bg = (const char*)Bt;
  uint32_t offA[4], offB[4];
#pragma unroll
  for (int r = 0; r < 4; ++r) {
    offA[r] = (uint32_t)(m0 + srow + r * 64) * (K_DIM * 2) + scol;
    offB[r] = (uint32_t)(n0 + srow + r * 64) * (K_DIM * 2) + scol;
  }
  uint32_t ktA = 0, ktB = 0;   // byte offset along K of next tile to stage (BK*2 = 128)

  f32x4 acc[8][4];
#pragma unroll
  for (int m = 0; m < 8; ++m)
#pragma unroll
    for (int n = 0; n < 4; ++n) {
      f32x4 z = {0.f, 0.f, 0.f, 0.f};
      acc[m][n] = z;
    }

  // ---- prologue: stage T0 (A+B) -> buf0; full drain
  SA(0, 0); SA(0, 1); SA(0, 2); SA(0, 3);
  SB(0, 0); SB(0, 1); SB(0, 2); SB(0, 3);
  ktA = 128; ktB = 128;
  VMCNT(0);
  BARRIER;

  bf16x8 a0[4][2], a1[4][2], b0[2][2], b1[2][2];

  for (int it = 0; it < NT / 2; ++it) {
    const int t0 = 2 * it;
    TILE_BODY(0, 1, t0);       // even tile: compute buf0, stage tile t+1 -> buf1
    TILE_BODY(1, 0, t0 + 1);   // odd tile:  compute buf1, stage tile t+1 -> buf0
  }

  // ---- epilogue: C/D map col=lane&15, row=(lane>>4)*4+j ; fuse *scale + bias
  const float scale = scale_p[0];
#pragma unroll
  for (int n = 0; n < 4; ++n) {
    const int col = n0 + wc * 64 + n * 16 + l15;
    const float bv = bias[col];
#pragma unroll
    for (int m = 0; m < 8; ++m) {
      const int r0 = m0 + wr * 128 + m * 16 + lhi * 4;
      float* op = out + (size_t)r0 * N_DIM + col;
#pragma unroll
      for (int j = 0; j < 4; ++j) op[(size_t)j * N_DIM] = acc[m][n][j] * scale + bv;
    }
  }
}

extern "C" void kernel_launch(void* const* d_in, const int* in_sizes, int n_in,
                              void* d_out, int out_size, void* d_ws, size_t ws_size,
                              hipStream_t stream) {
  (void)in_sizes; (void)n_in; (void)out_size; (void)ws_size;
  const float* x    = (const float*)d_in[0];   // [4][2048][2048] f32
  const float* w    = (const float*)d_in[1];   // [2048][2048] f32
  const float* bias = (const float*)d_in[2];   // [2048] f32
  float* out = (float*)d_out;                  // [4][2048][2048] f32

  float* partials = (float*)d_ws;                              // 1024 f32
  float* scale_slot = partials + 1024;                         // 1 f32
  unsigned short* wt = (unsigned short*)((char*)d_ws + 8192);  // 8 MB bf16 W_t
  unsigned short* xb = (unsigned short*)((char*)d_ws + 8192 + (size_t)N_DIM * K_DIM * 2);  // 32 MB

  cvt_x_absum<<<17408, 256, 0, stream>>>(x, xb, w, partials);
  quant_w<<<4096, 256, 0, stream>>>(w, partials, wt, scale_slot);
  gemm_bt<<<256, 512, 0, stream>>>(xb, wt, bias, scale_slot, out);
}

// Round 14
// 82.441 us; speedup vs baseline: 1.0356x; 1.0356x over previous
//
#include <hip/hip_runtime.h>
#include <hip/hip_bf16.h>
#include <stdint.h>

#define M_DIM 8192
#define N_DIM 2048
#define K_DIM 2048
#define NT    (K_DIM / 64)   // 32 K-tiles of BK=64

typedef float f32x4 __attribute__((ext_vector_type(4)));
typedef short bf16x8 __attribute__((ext_vector_type(8)));

typedef const __attribute__((address_space(1))) char* gp_t;
typedef __attribute__((address_space(3))) char* lp_t;

static __device__ __forceinline__ void gload_lds16(const void* g, void* l) {
  __builtin_amdgcn_global_load_lds((gp_t)(uintptr_t)g, (lp_t)(uint32_t)(uintptr_t)l, 16, 0, 0);
}

// round-to-nearest-even f32 -> bf16 bits (exact for -1, 0, +1)
static __device__ __forceinline__ unsigned short f2bf(float f) {
  unsigned int u = __float_as_uint(f);
  unsigned int r = (u + 0x7FFFu + ((u >> 16) & 1u)) >> 16;
  return (unsigned short)r;
}

// ---------------- fused: x -> bf16 (blocks 0..16383) + |W| partials (blocks 16384..17407) ----
__global__ void cvt_x_absum(const float* __restrict__ x, unsigned short* __restrict__ xb,
                            const float* __restrict__ w, float* __restrict__ partials) {
  const int b = blockIdx.x;
  if (b < 16384) {
    int tid = b * 256 + threadIdx.x;
    float4 v = ((const float4*)x)[tid];
    ushort4 o;
    o.x = f2bf(v.x); o.y = f2bf(v.y); o.z = f2bf(v.z); o.w = f2bf(v.w);
    ((ushort4*)xb)[tid] = o;
  } else {
    int tid = (b - 16384) * 256 + threadIdx.x;
    const float4* w4 = (const float4*)w;
    float s = 0.f;
#pragma unroll
    for (int i = 0; i < 4; ++i) {
      float4 v = w4[tid + i * 262144];
      s += fabsf(v.x) + fabsf(v.y) + fabsf(v.z) + fabsf(v.w);
    }
#pragma unroll
    for (int off = 32; off > 0; off >>= 1) s += __shfl_down(s, off, 64);
    __shared__ float ls[4];
    if ((threadIdx.x & 63) == 0) ls[threadIdx.x >> 6] = s;
    __syncthreads();
    if (threadIdx.x == 0) partials[b - 16384] = (ls[0] + ls[1]) + (ls[2] + ls[3]);
  }
}

// ---------------- W -> ternary bf16 {-1,0,1}; each block self-reduces scale ----------------
__global__ void quant_w(const float* __restrict__ w, const float* __restrict__ partials,
                        unsigned short* __restrict__ wt, float* __restrict__ scale_out) {
  __shared__ float ls[4];
  float s = 0.f;
#pragma unroll
  for (int i = 0; i < 4; ++i) s += partials[threadIdx.x + i * 256];
#pragma unroll
  for (int off = 32; off > 0; off >>= 1) s += __shfl_down(s, off, 64);
  if ((threadIdx.x & 63) == 0) ls[threadIdx.x >> 6] = s;
  __syncthreads();
  const float scale = ((ls[0] + ls[1]) + (ls[2] + ls[3])) * (1.0f / 4194304.0f);
  if (blockIdx.x == 0 && threadIdx.x == 0) scale_out[0] = scale;

  const float inv = 1.0f / (scale + 1e-10f);
  int tid = blockIdx.x * 256 + threadIdx.x;
  float4 v = ((const float4*)w)[tid];
  ushort4 o;
  float t;
  t = fminf(1.f, fmaxf(-1.f, rintf(v.x * inv))); o.x = f2bf(t);
  t = fminf(1.f, fmaxf(-1.f, rintf(v.y * inv))); o.y = f2bf(t);
  t = fminf(1.f, fmaxf(-1.f, rintf(v.z * inv))); o.z = f2bf(t);
  t = fminf(1.f, fmaxf(-1.f, rintf(v.w * inv))); o.w = f2bf(t);
  ((ushort4*)wt)[tid] = o;
}

// ---------------- 256x256 GEMM (r8 schedule; vmcnt moved after last MFMA cluster) ----------
// BM=BN=256, BK=64, 8 waves (2Mx4N), 512 thr, LDS 128KB dbuf, XOR swizzle (0 conflicts),
// counted vmcnt(4)/tile, 2 barriers/tile, K-loop x2 unrolled (compile-time buffer selects).
// vmcnt(4) placed AFTER MFMA_Q(1,1): the final 16-MFMA cluster covers residual drain latency
// (wait only has to precede the barrier).

#define VMCNT(n) asm volatile("s_waitcnt vmcnt(" #n ")" ::: "memory")
#define FENCE    asm volatile("" ::: "memory")
#define BARRIER  do { FENCE; __builtin_amdgcn_s_barrier(); FENCE; } while (0)

#define READ_A(base, mh, dst)                                                                   \
  do {                                                                                          \
    _Pragma("unroll") for (int i = 0; i < 4; ++i) {                                             \
      dst[i][0] = *(const bf16x8*)((base) + (wr * 128 + (mh) * 64 + i * 16) * 128 + rd0);       \
      dst[i][1] = *(const bf16x8*)((base) + (wr * 128 + (mh) * 64 + i * 16) * 128 + rd1);       \
    }                                                                                           \
  } while (0)

#define READ_B(base, nh, dst)                                                                   \
  do {                                                                                          \
    _Pragma("unroll") for (int j = 0; j < 2; ++j) {                                             \
      dst[j][0] = *(const bf16x8*)((base) + (wc * 64 + (nh) * 32 + j * 16) * 128 + rd0);        \
      dst[j][1] = *(const bf16x8*)((base) + (wc * 64 + (nh) * 32 + j * 16) * 128 + rd1);        \
    }                                                                                           \
  } while (0)

#define MFMA_Q(mh, nh, ar, br)                                                                  \
  do {                                                                                          \
    __builtin_amdgcn_s_setprio(1);                                                              \
    _Pragma("unroll") for (int i = 0; i < 4; ++i)                                               \
      _Pragma("unroll") for (int j = 0; j < 2; ++j)                                             \
        acc[(mh) * 4 + i][(nh) * 2 + j] = __builtin_amdgcn_mfma_f32_16x16x32_bf16(              \
            ar[i][0], br[j][0], acc[(mh) * 4 + i][(nh) * 2 + j], 0, 0, 0);                      \
    _Pragma("unroll") for (int i = 0; i < 4; ++i)                                               \
      _Pragma("unroll") for (int j = 0; j < 2; ++j)                                             \
        acc[(mh) * 4 + i][(nh) * 2 + j] = __builtin_amdgcn_mfma_f32_16x16x32_bf16(              \
            ar[i][1], br[j][1], acc[(mh) * 4 + i][(nh) * 2 + j], 0, 0, 0);                      \
    __builtin_amdgcn_s_setprio(0);                                                              \
  } while (0)

// stage half-tiles: linear LDS dest (gload_lds requirement), inverse-swizzled global source
#define SA(bufsel, r) gload_lds16(Ag + offA[r] + ktA, ldsb + (bufsel) * 65536 + tid * 16 + (r) * 8192)
#define SB(bufsel, r) gload_lds16(Bg + offB[r] + ktB, ldsb + (bufsel) * 65536 + 32768 + tid * 16 + (r) * 8192)

// one K-tile body (r8 schedule). CURSEL = this tile's buffer, NXTSEL = other buffer.
#define TILE_BODY(CURSEL, NXTSEL, t)                                                            \
  do {                                                                                          \
    const char* curA = ldsb + (CURSEL) * 65536;                                                 \
    const char* curB = curA + 32768;                                                            \
    READ_A(curA, 0, a0);                                                                        \
    READ_B(curB, 0, b0);                                                                        \
    if ((t) < NT - 1) { SA(NXTSEL, 0); SA(NXTSEL, 1); }                                         \
    MFMA_Q(0, 0, a0, b0);                                                                       \
    READ_B(curB, 1, b1);                                                                        \
    if ((t) < NT - 1) { SA(NXTSEL, 2); SA(NXTSEL, 3); ktA += 128; }                             \
    MFMA_Q(0, 1, a0, b1);                                                                       \
    BARRIER; /* all waves consumed B[t] (b0,b1 in regs) -> B-region may be overwritten */       \
    READ_A(curA, 1, a1);                                                                        \
    if ((t) < NT - 2) { SB(CURSEL, 0); SB(CURSEL, 1); }                                         \
    MFMA_Q(1, 0, a1, b0);                                                                       \
    if ((t) < NT - 2) { SB(CURSEL, 2); SB(CURSEL, 3); ktB += 128; }                             \
    MFMA_Q(1, 1, a1, b1);                                                                       \
    if ((t) < NT - 2) {                                                                         \
      VMCNT(4); /* oldest [T+1.B, T+1.A] land; newest 4 (T+2.B) stay in flight */               \
    } else {                                                                                    \
      VMCNT(0);                                                                                 \
    }                                                                                           \
    BARRIER; /* tile end: A[t] consumed; T(t+1) fully in LDS */                                 \
  } while (0)

__global__ void __launch_bounds__(512, 2)
gemm_bt(const unsigned short* __restrict__ A, const unsigned short* __restrict__ Bt,
        const float* __restrict__ bias, const float* __restrict__ scale_p,
        float* __restrict__ out) {
  __shared__ __align__(16) char lds_raw[131072];
  char* ldsb = (char*)lds_raw;

  const int tid = threadIdx.x;                 // 0..511
  const int lane = tid & 63;
  const int wid = tid >> 6;                    // 0..7
  const int wr = wid >> 2;                     // 0..1
  const int wc = wid & 3;                      // 0..3
  const int l15 = lane & 15, lhi = lane >> 4;

  // 3-bit read swizzle: byte ^= (row&7)<<4 ; row&7 == l15&7 (row offsets are x16)
  const int swzl = (l15 & 7) << 4;
  const int rd0 = l15 * 128 + ((lhi * 16) ^ swzl);          // k-half 0
  const int rd1 = l15 * 128 + (((lhi * 16) ^ 64) ^ swzl);   // k-half 1 (XOR, not +64!)

  // XCD-aware swizzle: 256 blocks, 8 XCDs x 32-chunk; bm-major inside chunk
  const int bid = blockIdx.x;
  const int swz = (bid & 7) * 32 + (bid >> 3);
  const int bm = swz >> 3;                     // 0..31
  const int bn = swz & 7;                      // 0..7
  const int m0 = bm << 8, n0 = bn << 8;

  // staging: thread stages LDS row srow+r*64, colbyte (tid&7)*16 (linear dest);
  // global source column inverse-swizzled so swizzled ds_reads see linear data.
  const int srow = tid >> 3;                                          // 0..63
  const int scol = (((tid & 7) ^ ((tid >> 3) & 7)) << 4);             // cb ^ (row&7)<<4
  const char* Ag = (const char*)A;
  const char* Bg = (const char*)Bt;
  uint32_t offA[4], offB[4];
#pragma unroll
  for (int r = 0; r < 4; ++r) {
    offA[r] = (uint32_t)(m0 + srow + r * 64) * (K_DIM * 2) + scol;
    offB[r] = (uint32_t)(n0 + srow + r * 64) * (K_DIM * 2) + scol;
  }
  uint32_t ktA = 0, ktB = 0;   // byte offset along K of next tile to stage (BK*2 = 128)

  f32x4 acc[8][4];
#pragma unroll
  for (int m = 0; m < 8; ++m)
#pragma unroll
    for (int n = 0; n < 4; ++n) {
      f32x4 z = {0.f, 0.f, 0.f, 0.f};
      acc[m][n] = z;
    }

  // ---- prologue: stage T0 (A+B -> buf0), T1.B -> buf1; drain T0, keep T1.B in flight
  SA(0, 0); SA(0, 1); SA(0, 2); SA(0, 3);
  SB(0, 0); SB(0, 1); SB(0, 2); SB(0, 3);
  ktB = 128;
  SB(1, 0); SB(1, 1); SB(1, 2); SB(1, 3);
  ktA = 128; ktB = 256;
  VMCNT(4);
  BARRIER;

  bf16x8 a0[4][2], a1[4][2], b0[2][2], b1[2][2];

  for (int it = 0; it < NT / 2; ++it) {
    const int t0 = 2 * it;
    TILE_BODY(0, 1, t0);       // even tile: compute buf0, stage A->buf1, B(t+2)->buf0
    TILE_BODY(1, 0, t0 + 1);   // odd tile:  compute buf1, stage A->buf0, B(t+2)->buf1
  }

  // ---- epilogue: C/D map col=lane&15, row=(lane>>4)*4+j ; fuse *scale + bias
  const float scale = scale_p[0];
#pragma unroll
  for (int n = 0; n < 4; ++n) {
    const int col = n0 + wc * 64 + n * 16 + l15;
    const float bv = bias[col];
#pragma unroll
    for (int m = 0; m < 8; ++m) {
      const int r0 = m0 + wr * 128 + m * 16 + lhi * 4;
      float* op = out + (size_t)r0 * N_DIM + col;
#pragma unroll
      for (int j = 0; j < 4; ++j) op[(size_t)j * N_DIM] = acc[m][n][j] * scale + bv;
    }
  }
}

extern "C" void kernel_launch(void* const* d_in, const int* in_sizes, int n_in,
                              void* d_out, int out_size, void* d_ws, size_t ws_size,
                              hipStream_t stream) {
  (void)in_sizes; (void)n_in; (void)out_size; (void)ws_size;
  const float* x    = (const float*)d_in[0];   // [4][2048][2048] f32
  const float* w    = (const float*)d_in[1];   // [2048][2048] f32
  const float* bias = (const float*)d_in[2];   // [2048] f32
  float* out = (float*)d_out;                  // [4][2048][2048] f32

  float* partials = (float*)d_ws;                              // 1024 f32
  float* scale_slot = partials + 1024;                         // 1 f32
  unsigned short* wt = (unsigned short*)((char*)d_ws + 8192);  // 8 MB bf16 W_t
  unsigned short* xb = (unsigned short*)((char*)d_ws + 8192 + (size_t)N_DIM * K_DIM * 2);  // 32 MB

  cvt_x_absum<<<17408, 256, 0, stream>>>(x, xb, w, partials);
  quant_w<<<4096, 256, 0, stream>>>(w, partials, wt, scale_slot);
  gemm_bt<<<256, 512, 0, stream>>>(xb, wt, bias, scale_slot, out);
}